// Round 8
// baseline (2191.854 us; speedup 1.0000x reference)
//
#include <hip/hip_runtime.h>
#include <math.h>

typedef unsigned int u32;
typedef unsigned short u16;

#define N_NODES 100000
#define N_EDGES 1000000
#define NB      64
#define NODES_PER_G 1562   // N // B; graph 63 holds 1594

typedef __attribute__((ext_vector_type(8))) short bf16x8;   // 8 bf16 = 4 VGPR
typedef __attribute__((ext_vector_type(4))) float f32x4;
#define MFMA16 __builtin_amdgcn_mfma_f32_16x16x32_bf16

__device__ __forceinline__ float sigmoidf_(float x){ return 1.f/(1.f+__expf(-x)); }
__device__ __forceinline__ float ftanh(float x){
  float e = __expf(-2.f*fabsf(x));
  float t = (1.f - e)/(1.f + e);
  return copysignf(t, x);
}
__device__ __forceinline__ float bfh(u16 h){ return __uint_as_float(((u32)h)<<16); }

__device__ __forceinline__ float dots(const float* w, const float* x){
  const float4* w4 = (const float4*)w;
  float a = 0.f;
#pragma unroll 8
  for(int i=0;i<32;i++){
    float4 t = w4[i];
    a = fmaf(t.x, x[4*i+0], a);
    a = fmaf(t.y, x[4*i+1], a);
    a = fmaf(t.z, x[4*i+2], a);
    a = fmaf(t.w, x[4*i+3], a);
  }
  return a;
}

// Dekker split: x = hi + lo, both bf16 (truncation); residual ~2^-16 relative
__device__ __forceinline__ void cvt2(float a, float b, u32 &hi, u32 &lo){
  u32 ab = __float_as_uint(a), bb = __float_as_uint(b);
  hi = (ab>>16) | (bb & 0xffff0000u);
  float ar = a - __uint_as_float(ab & 0xffff0000u);
  float br = b - __uint_as_float(bb & 0xffff0000u);
  lo = (__float_as_uint(ar)>>16) | (__float_as_uint(br) & 0xffff0000u);
}

// ------------- one-time weight split: fp32 -> bf16 hi/lo arrays in ws -------------
// flat u16 index:
// [0,32768)        E_w (128 x 256)
// [32768,49152)    gmA_w (128 x 128)
// [49152,147456)   GRU combined rows: row jr=j*128+h is 256 wide = [whh_jr | wih_jr]
// [147456,212992)  mA_w (512 x 128)
__global__ __launch_bounds__(256) void k_prep(const float* __restrict__ ew,
                    const float* __restrict__ ga,
                    const float* __restrict__ wih,
                    const float* __restrict__ whh,
                    const float* __restrict__ maw,
                    u16* __restrict__ hi, u16* __restrict__ lo){
  int i = blockIdx.x*256 + threadIdx.x;
  float x;
  if(i < 32768) x = ew[i];
  else if(i < 49152) x = ga[i-32768];
  else if(i < 147456){
    int rel = i - 49152;
    int jr = rel >> 8, c = rel & 255;
    x = (c < 128) ? whh[jr*128 + c] : wih[jr*128 + (c-128)];
  }
  else if(i < 212992) x = maw[i-147456];
  else return;
  u32 b = __float_as_uint(x);
  u16 h = (u16)(b>>16);
  float hf = __uint_as_float((u32)h<<16);
  float l = x - hf;
  hi[i] = h;
  lo[i] = (u16)(__float_as_uint(l)>>16);
}

// ---------------- per-graph precompute: s2s, s2m, w2(=dsup*mC), gmB_lin ----------
__global__ __launch_bounds__(128,4) void k_sup(const float* __restrict__ s,
                      const float* A_w, const float* A_b,
                      const float* C_w, const float* C_b,
                      const float* mB_w, const float* mB_b, const float* mC_w,
                      const float* gmB_w, const float* gmB_b,
                      float* s2s, float* s2m_g, float* w2, float* gmB_lin){
  int b = blockIdx.x, h = threadIdx.x;
  __shared__ float sb[128], s2ml[128];
  sb[h] = s[b*128+h];
  __syncthreads();
  s2s[b*128+h] = ftanh(dots(A_w + h*128, sb) + A_b[h]);
  float sm = ftanh(dots(C_w + h*128, sb) + C_b[h]);
  s2m_g[b*128+h] = sm; s2ml[h] = sm;
  for(int k=0;k<4;k++){
    float d = ftanh(dots(mB_w + (size_t)(k*128+h)*128, sb) + mB_b[k*128+h]);
    w2[b*512 + k*128 + h] = d * mC_w[k*128+h];
  }
  __syncthreads();
  gmB_lin[b*128+h] = dots(gmB_w + h*128, s2ml) + gmB_b[h];
}

// ---------------- CSR build: histogram, two-level scan, fill ----------------------
__global__ __launch_bounds__(256) void k_hist(const int* __restrict__ dst, u32* __restrict__ cnt){
  for(int i = blockIdx.x*256 + threadIdx.x; i < N_EDGES; i += 256*1024){
    int d = dst[i];
    if((u32)d < (u32)N_NODES) atomicAdd(&cnt[d], 1u);
  }
}

__global__ __launch_bounds__(1024) void k_scanA(const u32* __restrict__ cnt,
                        u32* __restrict__ offs, u32* __restrict__ tsum){
  __shared__ u32 wsum[16];
  int b = blockIdx.x, t = threadIdx.x, lane = t&63, w = t>>6;
  int i = b*1024 + t;
  u32 x = (i<N_NODES)? cnt[i] : 0u;
  u32 vsc = x;
#pragma unroll
  for(int o=1;o<64;o<<=1){ u32 y=__shfl_up(vsc,o,64); if(lane>=o) vsc+=y; }
  if(lane==63) wsum[w]=vsc;
  __syncthreads();
  if(w==0 && lane<16){
    u32 s = wsum[lane];
#pragma unroll
    for(int o=1;o<16;o<<=1){ u32 y=__shfl_up(s,o,64); if(lane>=o) s+=y; }
    wsum[lane]=s;
  }
  __syncthreads();
  u32 excl = (w>0 ? wsum[w-1] : 0u) + vsc - x;
  if(i<N_NODES) offs[i]=excl;
  if(t==1023) tsum[b] = wsum[15];
}

__global__ __launch_bounds__(1024) void k_scanB(const u32* __restrict__ tsum,
                        u32* __restrict__ offs, u32* __restrict__ cursor, int nb){
  __shared__ u32 base;
  int b = blockIdx.x, t = threadIdx.x;
  if(t==0){ u32 s=0; for(int j=0;j<b;j++) s+=tsum[j]; base=s; }
  __syncthreads();
  int i = b*1024 + t;
  if(i<N_NODES){ u32 o = offs[i]+base; offs[i]=o; cursor[i]=o; }
  if(b==nb-1 && t==0) offs[N_NODES] = base + tsum[b];
}

__global__ __launch_bounds__(256) void k_fill(const int* __restrict__ src, const int* __restrict__ dst,
                      u32* __restrict__ cursor, uint2* __restrict__ slots){
  for(int i = blockIdx.x*256 + threadIdx.x; i < N_EDGES; i += 256*1024){
    int d = dst[i];
    if((u32)d >= (u32)N_NODES) continue;
    int sj = src[i]; if((u32)sj >= (u32)N_NODES) sj = 0;
    u32 pos = atomicAdd(&cursor[d], 1u);
    slots[pos] = make_uint2((u32)sj, (u32)i);
  }
}

// ---------------- gather edge aggregation: one block per dst node ------------------
__global__ __launch_bounds__(128,8) void k_gath(const float* __restrict__ v,
                       const float* __restrict__ e,
                       const u32* __restrict__ offs, const uint2* __restrict__ slots,
                       const float* __restrict__ K_w, const float* __restrict__ K_b,
                       float* __restrict__ nbuf){
  int d = blockIdx.x;
  int h = threadIdx.x;
  u32 lo = offs[d], hi = offs[d+1];
  float4 kw0,kw1,kw2,kw3;
  { const float4* q=(const float4*)(K_w + h*16); kw0=q[0]; kw1=q[1]; kw2=q[2]; kw3=q[3]; }
  float kb = K_b[h];
  float acc = 0.f;
  __shared__ float el[16][16];
  __shared__ u32 ssrc[16];
  __shared__ u32 seid[16];
  for(u32 base=lo; base<hi; base+=16){
    int chunk = (int)(hi-base); if(chunk>16) chunk=16;
    if(h<chunk){ uint2 sd = slots[base+h]; ssrc[h]=sd.x; seid[h]=sd.y; }
    __syncthreads();
    for(int i=h; i<chunk*16; i+=128){ int j=i>>4, c=i&15; el[j][c] = e[(size_t)seid[j]*16 + c]; }
    __syncthreads();
    for(int j=0;j<chunk;j++){
      float kv = kb;
      kv=fmaf(kw0.x,el[j][0],kv);  kv=fmaf(kw0.y,el[j][1],kv);
      kv=fmaf(kw0.z,el[j][2],kv);  kv=fmaf(kw0.w,el[j][3],kv);
      kv=fmaf(kw1.x,el[j][4],kv);  kv=fmaf(kw1.y,el[j][5],kv);
      kv=fmaf(kw1.z,el[j][6],kv);  kv=fmaf(kw1.w,el[j][7],kv);
      kv=fmaf(kw2.x,el[j][8],kv);  kv=fmaf(kw2.y,el[j][9],kv);
      kv=fmaf(kw2.z,el[j][10],kv); kv=fmaf(kw2.w,el[j][11],kv);
      kv=fmaf(kw3.x,el[j][12],kv); kv=fmaf(kw3.y,el[j][13],kv);
      kv=fmaf(kw3.z,el[j][14],kv); kv=fmaf(kw3.w,el[j][15],kv);
      float vs = v[(size_t)ssrc[j]*128 + h];
      float val = kv*vs; val = (val>0.f)? val : 0.1f*val;
      acc += val;
    }
    __syncthreads();
  }
  nbuf[(size_t)d*128 + h] = acc;
}

// ---------------- fallback edge scatter (atomic), dst-range filtered ---------------
__global__ __launch_bounds__(128,4) void k_edge(const float* __restrict__ v, const float* __restrict__ e,
                       const int* __restrict__ src, const int* __restrict__ dst,
                       const float* K_w, const float* K_b,
                       float* __restrict__ nbuf, int lo, int hi){
  int h = threadIdx.x;
  int e0 = blockIdx.x * 16;
  __shared__ float el[16][16];
  __shared__ int sl[16], dl[16];
  for(int i=h;i<256;i+=128){ int ee=i>>4, c=i&15; el[ee][c]=e[(size_t)(e0+ee)*16+c]; }
  if(h<16){ sl[h]=src[e0+h]; dl[h]=dst[e0+h]; }
  float4 kw[4];
  { const float4* q=(const float4*)(K_w + h*16);
    kw[0]=q[0]; kw[1]=q[1]; kw[2]=q[2]; kw[3]=q[3]; }
  float kb = K_b[h];
  __syncthreads();
  for(int j=0;j<16;j++){
    int dj = dl[j];
    if(dj < lo || dj >= hi) continue;
    int sj = sl[j]; if((u32)sj >= (u32)N_NODES) sj = 0;
    float kv=kb;
#pragma unroll
    for(int i=0;i<4;i++){
      float4 t = kw[i];
      kv = fmaf(t.x, el[j][4*i+0], kv);
      kv = fmaf(t.y, el[j][4*i+1], kv);
      kv = fmaf(t.z, el[j][4*i+2], kv);
      kv = fmaf(t.w, el[j][4*i+3], kv);
    }
    float vs = v[(size_t)sj*128+h];
    float val = kv*vs; val = (val>0.f)? val : 0.1f*val;
    atomicAdd(&nbuf[(size_t)(dj-lo)*128+h], val);
  }
}

// ---------------- fused node pipeline + attention, 64 nodes/block -----------------
// 512 thr / 8 waves. Attention phase fused in (v already staged): wave wv computes
// head k=wv>>1, row-half=wv&1 of mA logits; halves combined in LDS; per-graph yg/asum
// via atomics with <=2 graph segments per block (b0 = boundary). Then m2m/gate/GRU as
// before (register-diet: fused r,z gates over K=256 [whh|wih] @ [hgate|v]).
__global__ __launch_bounds__(512,4) void k_node(
    const float* __restrict__ v, const int* __restrict__ graph_id,
    const u16* __restrict__ whi, const u16* __restrict__ wlo,
    const float* __restrict__ E_b, const float* __restrict__ gmA_b,
    const float* __restrict__ gmB_lin, const float* __restrict__ s2m_g,
    const float* __restrict__ bih, const float* __restrict__ bhh,
    const float* __restrict__ w2, const float* __restrict__ mA_b,
    const float* __restrict__ mC_b,
    float* __restrict__ asum, float* __restrict__ yg,
    const float* __restrict__ nbuf, float* __restrict__ out, int lo_, int lim){
  int t = threadIdx.x;
  int nl0 = blockIdx.x*64;
  int node0 = lo_ + nl0;
  int cnt = lim - nl0; if(cnt > 64) cnt = 64;
  int lane = t & 63, wv = t>>6;
  int lr = lane & 15, lg = lane >> 4;
  int koff = lg*8;
  int hh = wv*16 + lr;

  __shared__ u16 XH[64][264];   // cols 0..127: sve -> m2m -> hgate ; 128..255: v
  __shared__ u16 XL[64][264];
  __shared__ int gid[64];
  __shared__ float wl2[2][512];     // w2 for the (<=2) graphs in this block
  __shared__ float attp[4][2][64];  // per-head, per-row-half partial logits
  __shared__ float ael[64][4];
  __shared__ int b0s;

  for(int i=t; i<64*64; i+=512){
    int n = i>>6, c4 = i&63;
    float4 val;
    if(n < cnt){
      val = (c4<32) ? ((const float4*)(nbuf + (size_t)(nl0+n)*128))[c4]
                    : ((const float4*)(v + (size_t)(node0+n)*128))[c4-32];
    } else val = make_float4(0.f,0.f,0.f,0.f);
    int c = c4<<2;
    u32 h01,l01,h23,l23;
    cvt2(val.x, val.y, h01, l01);
    cvt2(val.z, val.w, h23, l23);
    *(uint2*)&XH[n][c] = make_uint2(h01, h23);
    *(uint2*)&XL[n][c] = make_uint2(l01, l23);
  }
  if(t<64) gid[t] = graph_id[node0 + ((t<cnt)? t : (cnt-1))] & 63;
  if(t==0) b0s = 64;
  __syncthreads();
  if(t>0 && t<64 && gid[t]!=gid[t-1]) b0s = t;   // at most one boundary
  __syncthreads();
  int b0 = b0s, gA = gid[0], gB = gid[63];
  wl2[0][t&511] = w2[gA*512 + (t&511)];
  wl2[1][t&511] = w2[gB*512 + (t&511)];
  __syncthreads();

  // ---- attention phase: logits for head k=wv>>1, row-half=wv&1 (4 row-tiles)
  {
    int k = wv>>1, half = wv&1;
    const u16* mAhi = whi + 147456;
    const u16* mAlo = wlo + 147456;
    float sr[4][4];
#pragma unroll
    for(int ng=0;ng<4;ng++){
#pragma unroll
      for(int r=0;r<4;r++) sr[ng][r]=0.f;
    }
#pragma unroll
    for(int tt=0; tt<4; tt++){
      int row = k*128 + (half*4+tt)*16 + lr;
      const u16* bh  = mAhi + (size_t)row*128 + koff;
      const u16* bl_ = mAlo + (size_t)row*128 + koff;
      bf16x8 wh[4], wl[4];
#pragma unroll
      for(int ks=0;ks<4;ks++){
        wh[ks] = *(const bf16x8*)(bh  + ks*32);
        wl[ks] = *(const bf16x8*)(bl_ + ks*32);
      }
      float bb = mA_b[row];
      float wA = wl2[0][row & 511], wB = wl2[1][row & 511];
#pragma unroll
      for(int ng=0;ng<4;ng++){
        f32x4 acc = {0.f,0.f,0.f,0.f};
#pragma unroll
        for(int ks=0;ks<4;ks++){
          bf16x8 ah = *(const bf16x8*)&XH[ng*16+lr][128 + koff + ks*32];
          bf16x8 al = *(const bf16x8*)&XL[ng*16+lr][128 + koff + ks*32];
          acc = MFMA16(ah, wh[ks], acc, 0,0,0);
          acc = MFMA16(ah, wl[ks], acc, 0,0,0);
          acc = MFMA16(al, wh[ks], acc, 0,0,0);
        }
#pragma unroll
        for(int r=0;r<4;r++){
          int n = ng*16 + lg*4 + r;
          float ww = (n >= b0) ? wB : wA;
          sr[ng][r] += ftanh(acc[r]+bb)*ww;
        }
      }
    }
#pragma unroll
    for(int ng=0;ng<4;ng++){
#pragma unroll
      for(int m=1;m<16;m<<=1){
        sr[ng][0] += __shfl_xor(sr[ng][0], m, 64);
        sr[ng][1] += __shfl_xor(sr[ng][1], m, 64);
        sr[ng][2] += __shfl_xor(sr[ng][2], m, 64);
        sr[ng][3] += __shfl_xor(sr[ng][3], m, 64);
      }
    }
    if(lr==0){
#pragma unroll
      for(int ng=0;ng<4;ng++)
#pragma unroll
        for(int r=0;r<4;r++) attp[k][half][ng*16+lg*4+r] = sr[ng][r];
    }
    __syncthreads();
    // exp + asum (one thread per (n,k))
    if(t < 256){
      int n = t & 63, kk = t >> 6;
      float ae = 0.f;
      if(n < cnt){
        ae = __expf(attp[kk][0][n] + attp[kk][1][n] + mC_b[kk]);
        atomicAdd(&asum[gid[n]*4 + kk], ae);
      }
      ael[n][kk] = ae;
    }
    __syncthreads();
    // y epilogue: thread (kk=t>>7, c=t&127), split into <=2 graph segments
    {
      int kk = t >> 7, c = t & 127;
      float yA = 0.f, yB = 0.f;
      for(int n=0; n<64; n++){
        float w = ael[n][kk];
        float vv = bfh(XH[n][128+c]) + bfh(XL[n][128+c]);
        if(n < b0) yA = fmaf(w, vv, yA); else yB = fmaf(w, vv, yB);
      }
      atomicAdd(&yg[(size_t)gA*512 + kk*128 + c], yA);
      if(b0 < 64) atomicAdd(&yg[(size_t)gB*512 + kk*128 + c], yB);
    }
    // no barrier needed: next phase only READS LDS written before earlier barriers
  }

  // ---- phase 1: m2m = leaky(E_w @ [sve; v] + E_b), K=256
  f32x4 m2m[4];
  {
    f32x4 acc[4];
#pragma unroll
    for(int ng=0;ng<4;ng++){ f32x4 z={0.f,0.f,0.f,0.f}; acc[ng]=z; }
    const u16* bh = whi + (size_t)hh*256 + koff;
    const u16* bl = wlo + (size_t)hh*256 + koff;
#pragma unroll
    for(int ks=0; ks<8; ks++){
      bf16x8 wh_ = *(const bf16x8*)(bh + ks*32);
      bf16x8 wl_ = *(const bf16x8*)(bl + ks*32);
#pragma unroll
      for(int ng=0;ng<4;ng++){
        bf16x8 ah = *(const bf16x8*)&XH[ng*16+lr][koff + ks*32];
        bf16x8 al = *(const bf16x8*)&XL[ng*16+lr][koff + ks*32];
        acc[ng] = MFMA16(ah, wh_, acc[ng], 0,0,0);
        acc[ng] = MFMA16(ah, wl_, acc[ng], 0,0,0);
        acc[ng] = MFMA16(al, wh_, acc[ng], 0,0,0);
      }
    }
    __syncthreads();   // all reads of XH/XL[0:256] (and y-epilogue reads) done
    float eb = E_b[hh];
#pragma unroll
    for(int ng=0;ng<4;ng++){
#pragma unroll
      for(int r=0;r<4;r++){
        float m = acc[ng][r] + eb;
        m = (m>0.f)? m : 0.1f*m;
        m2m[ng][r] = m;
        int n = ng*16 + lg*4 + r;
        u32 mb = __float_as_uint(m);
        u16 mh = (u16)(mb>>16);
        XH[n][hh] = mh;
        float mlr = m - __uint_as_float((u32)mh<<16);
        XL[n][hh] = (u16)(__float_as_uint(mlr)>>16);
      }
    }
    __syncthreads();
  }

  // ---- phase 2: z = sigmoid(gmA@m2m + gmA_b + gmB_lin); hgate = z*s2m + (1-z)*m2m
  {
    f32x4 acc[4];
#pragma unroll
    for(int ng=0;ng<4;ng++){ f32x4 z={0.f,0.f,0.f,0.f}; acc[ng]=z; }
    const u16* bh = whi + 32768 + (size_t)hh*128 + koff;
    const u16* bl = wlo + 32768 + (size_t)hh*128 + koff;
#pragma unroll
    for(int ks=0; ks<4; ks++){
      bf16x8 wh_ = *(const bf16x8*)(bh + ks*32);
      bf16x8 wl_ = *(const bf16x8*)(bl + ks*32);
#pragma unroll
      for(int ng=0;ng<4;ng++){
        bf16x8 ah = *(const bf16x8*)&XH[ng*16+lr][koff + ks*32];
        bf16x8 al = *(const bf16x8*)&XL[ng*16+lr][koff + ks*32];
        acc[ng] = MFMA16(ah, wh_, acc[ng], 0,0,0);
        acc[ng] = MFMA16(ah, wl_, acc[ng], 0,0,0);
        acc[ng] = MFMA16(al, wh_, acc[ng], 0,0,0);
      }
    }
    __syncthreads();
    float ab = gmA_b[hh];
#pragma unroll
    for(int ng=0;ng<4;ng++){
#pragma unroll
      for(int r=0;r<4;r++){
        int n = ng*16 + lg*4 + r;
        int g = gid[n];
        float z = sigmoidf_(acc[ng][r] + ab + gmB_lin[g*128+hh]);
        float hg = z*s2m_g[g*128+hh] + (1.f-z)*m2m[ng][r];
        u32 mb = __float_as_uint(hg);
        u16 mh = (u16)(mb>>16);
        XH[n][hh] = mh;
        float mlr = hg - __uint_as_float((u32)mh<<16);
        XL[n][hh] = (u16)(__float_as_uint(mlr)>>16);
      }
    }
    __syncthreads();
  }

  // ---- phase 3: GRU. combined rows [whh|wih] @ X=[hgate|v]; gates r, n, z --------
  {
    const u16* wGh = whi + 49152;
    const u16* wGl = wlo + 49152;
    f32x4 rr[4], nn[4];

    // gate r (j=0): fused K=256
    {
      f32x4 acc[4];
#pragma unroll
      for(int ng=0;ng<4;ng++){ f32x4 z={0.f,0.f,0.f,0.f}; acc[ng]=z; }
      const u16* ph = wGh + (size_t)hh*256 + koff;
      const u16* pl = wGl + (size_t)hh*256 + koff;
#pragma unroll
      for(int ks=0; ks<8; ks++){
        bf16x8 wh_ = *(const bf16x8*)(ph + ks*32);
        bf16x8 wl_ = *(const bf16x8*)(pl + ks*32);
#pragma unroll
        for(int ng=0;ng<4;ng++){
          bf16x8 ah = *(const bf16x8*)&XH[ng*16+lr][koff + ks*32];
          bf16x8 al = *(const bf16x8*)&XL[ng*16+lr][koff + ks*32];
          acc[ng] = MFMA16(ah, wh_, acc[ng], 0,0,0);
          acc[ng] = MFMA16(ah, wl_, acc[ng], 0,0,0);
          acc[ng] = MFMA16(al, wh_, acc[ng], 0,0,0);
        }
      }
      float bsum = bih[hh] + bhh[hh];
#pragma unroll
      for(int ng=0;ng<4;ng++)
#pragma unroll
        for(int r=0;r<4;r++) rr[ng][r] = sigmoidf_(acc[ng][r] + bsum);
    }

    // gate n (j=2): split halves (gh from hgate/whh, gi from v/wih)
    {
      f32x4 aH[4], aI[4];
#pragma unroll
      for(int ng=0;ng<4;ng++){ f32x4 z={0.f,0.f,0.f,0.f}; aH[ng]=z; aI[ng]=z; }
      const u16* ph = wGh + (size_t)(256+hh)*256 + koff;
      const u16* pl = wGl + (size_t)(256+hh)*256 + koff;
#pragma unroll
      for(int ks=0; ks<4; ks++){
        bf16x8 wh_ = *(const bf16x8*)(ph + ks*32);
        bf16x8 wl_ = *(const bf16x8*)(pl + ks*32);
#pragma unroll
        for(int ng=0;ng<4;ng++){
          bf16x8 ah = *(const bf16x8*)&XH[ng*16+lr][koff + ks*32];
          bf16x8 al = *(const bf16x8*)&XL[ng*16+lr][koff + ks*32];
          aH[ng] = MFMA16(ah, wh_, aH[ng], 0,0,0);
          aH[ng] = MFMA16(ah, wl_, aH[ng], 0,0,0);
          aH[ng] = MFMA16(al, wh_, aH[ng], 0,0,0);
        }
      }
#pragma unroll
      for(int ks=4; ks<8; ks++){
        bf16x8 wh_ = *(const bf16x8*)(ph + ks*32);
        bf16x8 wl_ = *(const bf16x8*)(pl + ks*32);
#pragma unroll
        for(int ng=0;ng<4;ng++){
          bf16x8 ah = *(const bf16x8*)&XH[ng*16+lr][koff + ks*32];
          bf16x8 al = *(const bf16x8*)&XL[ng*16+lr][koff + ks*32];
          aI[ng] = MFMA16(ah, wh_, aI[ng], 0,0,0);
          aI[ng] = MFMA16(ah, wl_, aI[ng], 0,0,0);
          aI[ng] = MFMA16(al, wh_, aI[ng], 0,0,0);
        }
      }
      float bI = bih[256+hh], bH = bhh[256+hh];
#pragma unroll
      for(int ng=0;ng<4;ng++)
#pragma unroll
        for(int r=0;r<4;r++)
          nn[ng][r] = ftanh((aI[ng][r]+bI) + rr[ng][r]*(aH[ng][r]+bH));
    }

    // gate z (j=1): fused K=256, then combine and write
    {
      f32x4 acc[4];
#pragma unroll
      for(int ng=0;ng<4;ng++){ f32x4 z={0.f,0.f,0.f,0.f}; acc[ng]=z; }
      const u16* ph = wGh + (size_t)(128+hh)*256 + koff;
      const u16* pl = wGl + (size_t)(128+hh)*256 + koff;
#pragma unroll
      for(int ks=0; ks<8; ks++){
        bf16x8 wh_ = *(const bf16x8*)(ph + ks*32);
        bf16x8 wl_ = *(const bf16x8*)(pl + ks*32);
#pragma unroll
        for(int ng=0;ng<4;ng++){
          bf16x8 ah = *(const bf16x8*)&XH[ng*16+lr][koff + ks*32];
          bf16x8 al = *(const bf16x8*)&XL[ng*16+lr][koff + ks*32];
          acc[ng] = MFMA16(ah, wh_, acc[ng], 0,0,0);
          acc[ng] = MFMA16(ah, wl_, acc[ng], 0,0,0);
          acc[ng] = MFMA16(al, wh_, acc[ng], 0,0,0);
        }
      }
      float bsum = bih[128+hh] + bhh[128+hh];
#pragma unroll
      for(int ng=0;ng<4;ng++){
#pragma unroll
        for(int r=0;r<4;r++){
          float zz = sigmoidf_(acc[ng][r] + bsum);
          int n = ng*16 + lg*4 + r;
          float hgv = bfh(XH[n][hh]) + bfh(XL[n][hh]);   // exact hi+lo reconstruct
          if(n < cnt)
            out[(size_t)(node0+n)*128 + hh] = (1.f-zz)*nn[ng][r] + zz*hgv;
        }
      }
    }
  }
}

// ---------------- supernode finish: m2s (incl. hoisted mD), gate, GRU -------------
__global__ __launch_bounds__(128,4) void k_sup2(const float* __restrict__ s,
                       const float* __restrict__ yg, const float* __restrict__ asum,
                       const float* __restrict__ s2s,
                       const float* mD_w, const float* mD_b,
                       const float* B_w, const float* B_b,
                       const float* gsA_w, const float* gsA_b,
                       const float* gsB_w, const float* gsB_b,
                       const float* wih, const float* bih, const float* whh, const float* bhh,
                       float* __restrict__ out){
  int b=blockIdx.x, h=threadIdx.x;
  __shared__ float ygl[512], m2si[512], m2sl[128], s2sl[128], sl[128], hgl[128];
  for(int j=0;j<4;j++){ int kh=h+j*128; ygl[kh]=yg[b*512+kh]; }
  s2sl[h]=s2s[b*128+h];
  sl[h]=s[b*128+h];
  __syncthreads();
  for(int j=0;j<4;j++){
    int kh=h+j*128; int k=kh>>7;
    m2si[kh] = dots(mD_w + (size_t)kh*128, &ygl[k*128]) / asum[b*4+k] + mD_b[kh];
  }
  __syncthreads();
  float acc = B_b[h];
  { const float4* q=(const float4*)(B_w + (size_t)h*512);
#pragma unroll 8
    for(int i=0;i<128;i++){
      float4 p=q[i]; int base=i*4;
      acc=fmaf(p.x,m2si[base+0],acc); acc=fmaf(p.y,m2si[base+1],acc);
      acc=fmaf(p.z,m2si[base+2],acc); acc=fmaf(p.w,m2si[base+3],acc);
    }
  }
  float m2sv = ftanh(acc);
  m2sl[h]=m2sv;
  __syncthreads();
  float zacc = dots(gsA_w+(size_t)h*128, s2sl) + gsA_b[h];
  zacc      += dots(gsB_w+(size_t)h*128, m2sl) + gsB_b[h];
  float z = sigmoidf_(zacc);
  float hg = z*m2sl[h] + (1.f-z)*s2sl[h];
  hgl[h]=hg;
  __syncthreads();
  float gi[3], gh[3];
  for(int j=0;j<3;j++){
    gi[j]=dots(wih+(size_t)(h+j*128)*128, sl)+bih[h+j*128];
    gh[j]=dots(whh+(size_t)(h+j*128)*128, hgl)+bhh[h+j*128];
  }
  float r=sigmoidf_(gi[0]+gh[0]), z2=sigmoidf_(gi[1]+gh[1]);
  float nn=ftanh(gi[2]+r*gh[2]);
  out[(size_t)N_NODES*128 + b*128 + h] = (1.f-z2)*nn + z2*hg;
}

extern "C" void kernel_launch(void* const* d_in, const int* in_sizes, int n_in,
                              void* d_out, int out_size, void* d_ws, size_t ws_size,
                              hipStream_t stream){
  const float* v   = (const float*)d_in[0];
  const float* e   = (const float*)d_in[1];
  const float* s   = (const float*)d_in[2];
  const int* src  = (const int*)d_in[3];
  const int* dst  = (const int*)d_in[4];
  const int* graph_id = (const int*)d_in[5];
  const float* A_w=(const float*)d_in[6];  const float* A_b=(const float*)d_in[7];
  const float* B_w=(const float*)d_in[8];  const float* B_b=(const float*)d_in[9];
  const float* C_w=(const float*)d_in[10]; const float* C_b=(const float*)d_in[11];
  const float* E_w=(const float*)d_in[12]; const float* E_b=(const float*)d_in[13];
  const float* K_w=(const float*)d_in[14]; const float* K_b=(const float*)d_in[15];
  const float* mA_w=(const float*)d_in[16]; const float* mA_b=(const float*)d_in[17];
  const float* mB_w=(const float*)d_in[18]; const float* mB_b=(const float*)d_in[19];
  const float* mC_w=(const float*)d_in[20]; const float* mC_b=(const float*)d_in[21];
  const float* mD_w=(const float*)d_in[22]; const float* mD_b=(const float*)d_in[23];
  const float* gmA_w=(const float*)d_in[24]; const float* gmA_b=(const float*)d_in[25];
  const float* gmB_w=(const float*)d_in[26]; const float* gmB_b=(const float*)d_in[27];
  const float* gm_wih=(const float*)d_in[28]; const float* gm_bih=(const float*)d_in[29];
  const float* gm_whh=(const float*)d_in[30]; const float* gm_bhh=(const float*)d_in[31];
  const float* gsA_w=(const float*)d_in[32]; const float* gsA_b=(const float*)d_in[33];
  const float* gsB_w=(const float*)d_in[34]; const float* gsB_b=(const float*)d_in[35];
  const float* gs_wih=(const float*)d_in[36]; const float* gs_bih=(const float*)d_in[37];
  const float* gs_whh=(const float*)d_in[38]; const float* gs_bhh=(const float*)d_in[39];

  float* ws = (float*)d_ws;
  float* asum    = ws;                  // 256
  float* yg      = asum + 256;          // 32768
  float* s2s     = yg + 32768;          // 8192
  float* s2m_g   = s2s + 8192;          // 8192
  float* gmB_lin = s2m_g + 8192;        // 8192
  float* w2      = gmB_lin + 8192;      // 32768
  u16*   whi     = (u16*)(w2 + 32768);  // 212992 u16 (hi)
  u16*   wlo     = whi + 212992;        // 212992 u16 (lo)
  const size_t small_f = 256 + 32768 + 8192*3 + 32768 + 212992;   // 303360 floats

  size_t ws_f = ws_size / 4;

  hipMemsetAsync(asum, 0, (256 + 32768) * sizeof(float), stream);

  k_prep<<<832, 256, 0, stream>>>(E_w, gmA_w, gm_wih, gm_whh, mA_w, whi, wlo);
  k_sup <<<NB, 128, 0, stream>>>(s, A_w,A_b, C_w,C_b, mB_w,mB_b,mC_w, gmB_w,gmB_b,
                                 s2s, s2m_g, w2, gmB_lin);

  // CSR-gather path: offs(100002) + cursor(100002) + tsum(128) + slots(1M uint2) + nbuf
  const int SCAN_NB = (N_NODES + 1023) / 1024;         // 98
  const size_t csr_off = small_f;
  const size_t csr_f   = 100002 + 100002 + 128 + 2000000;
  const size_t need_csr = csr_off + csr_f + (size_t)N_NODES*128;

  if(ws_f >= need_csr){
    u32*   offs   = (u32*)(ws + csr_off);
    u32*   cursor = offs + 100002;
    u32*   tsum   = cursor + 100002;
    uint2* slots  = (uint2*)(tsum + 128);
    float* nbuf   = (float*)(slots + 1000000);
    hipMemsetAsync(cursor, 0, (size_t)N_NODES*sizeof(u32), stream);
    k_hist<<<1024, 256, 0, stream>>>(dst, cursor);
    k_scanA<<<SCAN_NB, 1024, 0, stream>>>(cursor, offs, tsum);
    k_scanB<<<SCAN_NB, 1024, 0, stream>>>(tsum, offs, cursor, SCAN_NB);
    k_fill<<<1024, 256, 0, stream>>>(src, dst, cursor, slots);
    k_gath<<<N_NODES, 128, 0, stream>>>(v, e, offs, slots, K_w, K_b, nbuf);
    k_node<<<(N_NODES+63)/64, 512, 0, stream>>>(v, graph_id, whi, wlo, E_b, gmA_b,
                                                gmB_lin, s2m_g, gm_bih, gm_bhh,
                                                w2, mA_b, mC_b, asum, yg,
                                                nbuf, (float*)d_out, 0, N_NODES);
  } else {
    // fallback: chunked atomic scatter
    float* nbuf = (float*)(wlo + 212992);
    long avail = (ws_f > small_f) ? (long)(ws_f - small_f) : 0;
    long M = (avail / 128) & ~63L;
    if(M > N_NODES) M = N_NODES;
    if(M < 64) M = 64;
    for(long lo = 0; lo < N_NODES; lo += M){
      long cnt = N_NODES - lo; if(cnt > M) cnt = M;
      int ilo = (int)lo, icnt = (int)cnt;
      hipMemsetAsync(nbuf, 0, (size_t)icnt*128*sizeof(float), stream);
      k_edge<<<N_EDGES/16, 128, 0, stream>>>(v, e, src, dst, K_w, K_b, nbuf, ilo, ilo+icnt);
      k_node<<<(icnt+63)/64, 512, 0, stream>>>(v, graph_id, whi, wlo, E_b, gmA_b,
                                               gmB_lin, s2m_g, gm_bih, gm_bhh,
                                               w2, mA_b, mC_b, asum, yg,
                                               nbuf, (float*)d_out, ilo, icnt);
    }
  }

  k_sup2<<<NB, 128, 0, stream>>>(s, yg, asum, s2s, mD_w, mD_b, B_w,B_b,
                                 gsA_w,gsA_b, gsB_w,gsB_b,
                                 gs_wih,gs_bih, gs_whh,gs_bhh, (float*)d_out);
}

// Round 9
// 968.083 us; speedup vs baseline: 2.2641x; 2.2641x over previous
//
#include <hip/hip_runtime.h>
#include <math.h>

typedef unsigned int u32;
typedef unsigned short u16;

#define N_NODES 100000
#define N_EDGES 1000000
#define NB      64
#define NODES_PER_G 1562   // N // B; graph 63 holds 1594
#define CH128 13           // ceil(1594/128)

typedef __attribute__((ext_vector_type(8))) short bf16x8;   // 8 bf16 = 4 VGPR
typedef __attribute__((ext_vector_type(4))) float f32x4;
#define MFMA16 __builtin_amdgcn_mfma_f32_16x16x32_bf16

__device__ __forceinline__ float sigmoidf_(float x){ return 1.f/(1.f+__expf(-x)); }
__device__ __forceinline__ float ftanh(float x){
  float e = __expf(-2.f*fabsf(x));
  float t = (1.f - e)/(1.f + e);
  return copysignf(t, x);
}
__device__ __forceinline__ float bfh(u16 h){ return __uint_as_float(((u32)h)<<16); }

__device__ __forceinline__ float dots(const float* w, const float* x){
  const float4* w4 = (const float4*)w;
  float a = 0.f;
#pragma unroll 8
  for(int i=0;i<32;i++){
    float4 t = w4[i];
    a = fmaf(t.x, x[4*i+0], a);
    a = fmaf(t.y, x[4*i+1], a);
    a = fmaf(t.z, x[4*i+2], a);
    a = fmaf(t.w, x[4*i+3], a);
  }
  return a;
}

// Dekker split: x = hi + lo, both bf16 (truncation); residual ~2^-16 relative
__device__ __forceinline__ void cvt2(float a, float b, u32 &hi, u32 &lo){
  u32 ab = __float_as_uint(a), bb = __float_as_uint(b);
  hi = (ab>>16) | (bb & 0xffff0000u);
  float ar = a - __uint_as_float(ab & 0xffff0000u);
  float br = b - __uint_as_float(bb & 0xffff0000u);
  lo = (__float_as_uint(ar)>>16) | (__float_as_uint(br) & 0xffff0000u);
}

// ------------- one-time weight split: fp32 -> bf16 hi/lo arrays in ws -------------
// flat u16 index:
// [0,32768)        E_w (128 x 256)
// [32768,49152)    gmA_w (128 x 128)
// [49152,147456)   GRU combined rows: row jr=j*128+h is 256 wide = [whh_jr | wih_jr]
// [147456,212992)  mA_w (512 x 128)
__global__ __launch_bounds__(256) void k_prep(const float* __restrict__ ew,
                    const float* __restrict__ ga,
                    const float* __restrict__ wih,
                    const float* __restrict__ whh,
                    const float* __restrict__ maw,
                    u16* __restrict__ hi, u16* __restrict__ lo){
  int i = blockIdx.x*256 + threadIdx.x;
  float x;
  if(i < 32768) x = ew[i];
  else if(i < 49152) x = ga[i-32768];
  else if(i < 147456){
    int rel = i - 49152;
    int jr = rel >> 8, c = rel & 255;
    x = (c < 128) ? whh[jr*128 + c] : wih[jr*128 + (c-128)];
  }
  else if(i < 212992) x = maw[i-147456];
  else return;
  u32 b = __float_as_uint(x);
  u16 h = (u16)(b>>16);
  float hf = __uint_as_float((u32)h<<16);
  float l = x - hf;
  hi[i] = h;
  lo[i] = (u16)(__float_as_uint(l)>>16);
}

// ---------------- per-graph precompute: s2s, s2m, w2(=dsup*mC), gmB_lin ----------
__global__ __launch_bounds__(128,4) void k_sup(const float* __restrict__ s,
                      const float* A_w, const float* A_b,
                      const float* C_w, const float* C_b,
                      const float* mB_w, const float* mB_b, const float* mC_w,
                      const float* gmB_w, const float* gmB_b,
                      float* s2s, float* s2m_g, float* w2, float* gmB_lin){
  int b = blockIdx.x, h = threadIdx.x;
  __shared__ float sb[128], s2ml[128];
  sb[h] = s[b*128+h];
  __syncthreads();
  s2s[b*128+h] = ftanh(dots(A_w + h*128, sb) + A_b[h]);
  float sm = ftanh(dots(C_w + h*128, sb) + C_b[h]);
  s2m_g[b*128+h] = sm; s2ml[h] = sm;
  for(int k=0;k<4;k++){
    float d = ftanh(dots(mB_w + (size_t)(k*128+h)*128, sb) + mB_b[k*128+h]);
    w2[b*512 + k*128 + h] = d * mC_w[k*128+h];
  }
  __syncthreads();
  gmB_lin[b*128+h] = dots(gmB_w + h*128, s2ml) + gmB_b[h];
}

// ------------- attention logits + weighted node-sum y, 128 nodes/block ------------
// 512 thr / 8 waves; wave wv = (head k=wv>>1, row-half=wv&1). Per weight tile tt,
// 8 node-group MFMA chains reuse the same fragments (2x weight amortization vs r7).
// __launch_bounds__(512,2): VGPR cap 256 -> no spill (round-8 lesson).
__global__ __launch_bounds__(512,2) void k_att(const float* __restrict__ v,
                      const float* __restrict__ w2,
                      const u16* __restrict__ mAhi, const u16* __restrict__ mAlo,
                      const float* __restrict__ mA_b, const float* __restrict__ mC_b,
                      float* __restrict__ asum, float* __restrict__ yg){
  int g = blockIdx.x / CH128, chunk = blockIdx.x % CH128;
  int start = g*NODES_PER_G, end = (g==NB-1)? N_NODES : start+NODES_PER_G;
  int node0 = start + chunk*128;
  int cnt = end - node0; if(cnt<=0) return; if(cnt>128) cnt=128;
  int t = threadIdx.x;
  int lane = t & 63, wv = t>>6;
  int lr = lane & 15, lg = lane >> 4;
  int koff = lg*8;

  __shared__ u16 XH[128][136], XL[128][136];   // 272B row stride
  __shared__ float ael[128][4];
  __shared__ float attp[4][2][128];            // per-head, per-row-half partials
  __shared__ float yq[8][4][128];              // per-16-node-group partial y
  __shared__ float wl2s[512], bAs[512];

  for(int i=t;i<128*32;i+=512){
    int n=i>>5, c=i&31;
    float4 val = (n<cnt) ? ((const float4*)(v + (size_t)(node0+n)*128))[c]
                         : make_float4(0.f,0.f,0.f,0.f);
    int cc = c<<2;
    u32 h01,l01,h23,l23;
    cvt2(val.x,val.y,h01,l01); cvt2(val.z,val.w,h23,l23);
    *(uint2*)&XH[n][cc] = make_uint2(h01,h23);
    *(uint2*)&XL[n][cc] = make_uint2(l01,l23);
  }
  { wl2s[t]=w2[g*512+t]; bAs[t]=mA_b[t]; }
  __syncthreads();

  int k = wv>>1, half = wv&1;
  float sr[8][4];
#pragma unroll
  for(int ng=0;ng<8;ng++){
#pragma unroll
    for(int r=0;r<4;r++) sr[ng][r]=0.f;
  }

  for(int tt=0; tt<4; tt++){
    int row = k*128 + (half*4+tt)*16 + lr;
    const u16* bh  = mAhi + (size_t)row*128 + koff;
    const u16* bl_ = mAlo + (size_t)row*128 + koff;
    bf16x8 wh[4], wl[4];
#pragma unroll
    for(int ks=0;ks<4;ks++){
      wh[ks] = *(const bf16x8*)(bh  + ks*32);
      wl[ks] = *(const bf16x8*)(bl_ + ks*32);
    }
    float bb = bAs[row], ww = wl2s[row];
#pragma unroll
    for(int ng=0;ng<8;ng++){
      const u16* pah = &XH[ng*16+lr][koff];
      const u16* pal = &XL[ng*16+lr][koff];
      f32x4 acc = {0.f,0.f,0.f,0.f};
#pragma unroll
      for(int ks=0;ks<4;ks++){
        bf16x8 ah = *(const bf16x8*)(pah + ks*32);
        bf16x8 al = *(const bf16x8*)(pal + ks*32);
        acc = MFMA16(ah, wh[ks], acc, 0,0,0);
        acc = MFMA16(ah, wl[ks], acc, 0,0,0);
        acc = MFMA16(al, wh[ks], acc, 0,0,0);
      }
#pragma unroll
      for(int r=0;r<4;r++) sr[ng][r] += ftanh(acc[r]+bb)*ww;
    }
  }
  // reduce over the 16 col-lanes (weight rows within tile)
#pragma unroll
  for(int ng=0;ng<8;ng++){
#pragma unroll
    for(int m=1;m<16;m<<=1){
      sr[ng][0] += __shfl_xor(sr[ng][0], m, 64);
      sr[ng][1] += __shfl_xor(sr[ng][1], m, 64);
      sr[ng][2] += __shfl_xor(sr[ng][2], m, 64);
      sr[ng][3] += __shfl_xor(sr[ng][3], m, 64);
    }
  }
  if(lr==0){
#pragma unroll
    for(int ng=0;ng<8;ng++)
#pragma unroll
      for(int r=0;r<4;r++) attp[k][half][ng*16+lg*4+r] = sr[ng][r];
  }
  __syncthreads();

  // exp + ael; asum via wave-reduced atomic (kk uniform per wave)
  {
    int n = t & 127, kk = t >> 7;
    float ae = 0.f;
    if(n < cnt) ae = __expf(attp[kk][0][n] + attp[kk][1][n] + mC_b[kk]);
    ael[n][kk] = ae;
    float s = ae;
#pragma unroll
    for(int o=32;o>0;o>>=1) s += __shfl_xor(s, o, 64);
    if(lane==0) atomicAdd(&asum[g*4+kk], s);
  }
  __syncthreads();

  // yq partials: q=t>>6 (16 nodes), kk=(t>>4)&3, co=t&15 (8 cols each)
  {
    int q = t>>6, kk = (t>>4)&3, co = t&15;
    float a8[8];
#pragma unroll
    for(int j=0;j<8;j++) a8[j]=0.f;
    for(int n=q*16; n<q*16+16; n++){
      float w = ael[n][kk];
      bf16x8 hh = *(const bf16x8*)&XH[n][co*8];
      bf16x8 ll = *(const bf16x8*)&XL[n][co*8];
#pragma unroll
      for(int j=0;j<8;j++){
        float vv = bfh((u16)hh[j]) + bfh((u16)ll[j]);
        a8[j] = fmaf(w, vv, a8[j]);
      }
    }
#pragma unroll
    for(int j=0;j<8;j++) yq[q][kk][co*8+j] = a8[j];
  }
  __syncthreads();
  {
    int c = t&127, kk = t>>7;
    float y = 0.f;
#pragma unroll
    for(int q=0;q<8;q++) y += yq[q][kk][c];
    atomicAdd(&yg[(size_t)g*512 + kk*128 + c], y);
  }
}

// ---------------- CSR build: histogram, two-level scan, fill ----------------------
__global__ __launch_bounds__(256) void k_hist(const int* __restrict__ dst, u32* __restrict__ cnt){
  for(int i = blockIdx.x*256 + threadIdx.x; i < N_EDGES; i += 256*1024){
    int d = dst[i];
    if((u32)d < (u32)N_NODES) atomicAdd(&cnt[d], 1u);
  }
}

__global__ __launch_bounds__(1024) void k_scanA(const u32* __restrict__ cnt,
                        u32* __restrict__ offs, u32* __restrict__ tsum){
  __shared__ u32 wsum[16];
  int b = blockIdx.x, t = threadIdx.x, lane = t&63, w = t>>6;
  int i = b*1024 + t;
  u32 x = (i<N_NODES)? cnt[i] : 0u;
  u32 vsc = x;
#pragma unroll
  for(int o=1;o<64;o<<=1){ u32 y=__shfl_up(vsc,o,64); if(lane>=o) vsc+=y; }
  if(lane==63) wsum[w]=vsc;
  __syncthreads();
  if(w==0 && lane<16){
    u32 s = wsum[lane];
#pragma unroll
    for(int o=1;o<16;o<<=1){ u32 y=__shfl_up(s,o,64); if(lane>=o) s+=y; }
    wsum[lane]=s;
  }
  __syncthreads();
  u32 excl = (w>0 ? wsum[w-1] : 0u) + vsc - x;
  if(i<N_NODES) offs[i]=excl;
  if(t==1023) tsum[b] = wsum[15];
}

__global__ __launch_bounds__(1024) void k_scanB(const u32* __restrict__ tsum,
                        u32* __restrict__ offs, u32* __restrict__ cursor, int nb){
  __shared__ u32 base;
  int b = blockIdx.x, t = threadIdx.x;
  if(t==0){ u32 s=0; for(int j=0;j<b;j++) s+=tsum[j]; base=s; }
  __syncthreads();
  int i = b*1024 + t;
  if(i<N_NODES){ u32 o = offs[i]+base; offs[i]=o; cursor[i]=o; }
  if(b==nb-1 && t==0) offs[N_NODES] = base + tsum[b];
}

__global__ __launch_bounds__(256) void k_fill(const int* __restrict__ src, const int* __restrict__ dst,
                      u32* __restrict__ cursor, uint2* __restrict__ slots){
  for(int i = blockIdx.x*256 + threadIdx.x; i < N_EDGES; i += 256*1024){
    int d = dst[i];
    if((u32)d >= (u32)N_NODES) continue;
    int sj = src[i]; if((u32)sj >= (u32)N_NODES) sj = 0;
    u32 pos = atomicAdd(&cursor[d], 1u);
    slots[pos] = make_uint2((u32)sj, (u32)i);
  }
}

// ---------------- gather edge aggregation: one block per dst node ------------------
__global__ __launch_bounds__(128,8) void k_gath(const float* __restrict__ v,
                       const float* __restrict__ e,
                       const u32* __restrict__ offs, const uint2* __restrict__ slots,
                       const float* __restrict__ K_w, const float* __restrict__ K_b,
                       float* __restrict__ nbuf){
  int d = blockIdx.x;
  int h = threadIdx.x;
  u32 lo = offs[d], hi = offs[d+1];
  float4 kw0,kw1,kw2,kw3;
  { const float4* q=(const float4*)(K_w + h*16); kw0=q[0]; kw1=q[1]; kw2=q[2]; kw3=q[3]; }
  float kb = K_b[h];
  float acc = 0.f;
  __shared__ float el[16][16];
  __shared__ u32 ssrc[16];
  __shared__ u32 seid[16];
  for(u32 base=lo; base<hi; base+=16){
    int chunk = (int)(hi-base); if(chunk>16) chunk=16;
    if(h<chunk){ uint2 sd = slots[base+h]; ssrc[h]=sd.x; seid[h]=sd.y; }
    __syncthreads();
    for(int i=h; i<chunk*16; i+=128){ int j=i>>4, c=i&15; el[j][c] = e[(size_t)seid[j]*16 + c]; }
    __syncthreads();
    for(int j=0;j<chunk;j++){
      float kv = kb;
      kv=fmaf(kw0.x,el[j][0],kv);  kv=fmaf(kw0.y,el[j][1],kv);
      kv=fmaf(kw0.z,el[j][2],kv);  kv=fmaf(kw0.w,el[j][3],kv);
      kv=fmaf(kw1.x,el[j][4],kv);  kv=fmaf(kw1.y,el[j][5],kv);
      kv=fmaf(kw1.z,el[j][6],kv);  kv=fmaf(kw1.w,el[j][7],kv);
      kv=fmaf(kw2.x,el[j][8],kv);  kv=fmaf(kw2.y,el[j][9],kv);
      kv=fmaf(kw2.z,el[j][10],kv); kv=fmaf(kw2.w,el[j][11],kv);
      kv=fmaf(kw3.x,el[j][12],kv); kv=fmaf(kw3.y,el[j][13],kv);
      kv=fmaf(kw3.z,el[j][14],kv); kv=fmaf(kw3.w,el[j][15],kv);
      float vs = v[(size_t)ssrc[j]*128 + h];
      float val = kv*vs; val = (val>0.f)? val : 0.1f*val;
      acc += val;
    }
    __syncthreads();
  }
  nbuf[(size_t)d*128 + h] = acc;
}

// ---------------- fallback edge scatter (atomic), dst-range filtered ---------------
__global__ __launch_bounds__(128,4) void k_edge(const float* __restrict__ v, const float* __restrict__ e,
                       const int* __restrict__ src, const int* __restrict__ dst,
                       const float* K_w, const float* K_b,
                       float* __restrict__ nbuf, int lo, int hi){
  int h = threadIdx.x;
  int e0 = blockIdx.x * 16;
  __shared__ float el[16][16];
  __shared__ int sl[16], dl[16];
  for(int i=h;i<256;i+=128){ int ee=i>>4, c=i&15; el[ee][c]=e[(size_t)(e0+ee)*16+c]; }
  if(h<16){ sl[h]=src[e0+h]; dl[h]=dst[e0+h]; }
  float4 kw[4];
  { const float4* q=(const float4*)(K_w + h*16);
    kw[0]=q[0]; kw[1]=q[1]; kw[2]=q[2]; kw[3]=q[3]; }
  float kb = K_b[h];
  __syncthreads();
  for(int j=0;j<16;j++){
    int dj = dl[j];
    if(dj < lo || dj >= hi) continue;
    int sj = sl[j]; if((u32)sj >= (u32)N_NODES) sj = 0;
    float kv=kb;
#pragma unroll
    for(int i=0;i<4;i++){
      float4 t = kw[i];
      kv = fmaf(t.x, el[j][4*i+0], kv);
      kv = fmaf(t.y, el[j][4*i+1], kv);
      kv = fmaf(t.z, el[j][4*i+2], kv);
      kv = fmaf(t.w, el[j][4*i+3], kv);
    }
    float vs = v[(size_t)sj*128+h];
    float val = kv*vs; val = (val>0.f)? val : 0.1f*val;
    atomicAdd(&nbuf[(size_t)(dj-lo)*128+h], val);
  }
}

// ---------------- fused node pipeline, 64 nodes/block, register-diet GRU ----------
// 512 thr / 8 waves; wave wv owns h-tile wv for all phases, ng=0..3 node groups.
// GRU r,z gates fused via K=256 combined weights [whh|wih] @ [hgate|v] (one acc set);
// n gate split (needs gi,gh separately). hgate reconstructed from LDS hi+lo at the end.
__global__ __launch_bounds__(512,4) void k_node(
    const float* __restrict__ v, const int* __restrict__ graph_id,
    const u16* __restrict__ whi, const u16* __restrict__ wlo,
    const float* __restrict__ E_b, const float* __restrict__ gmA_b,
    const float* __restrict__ gmB_lin, const float* __restrict__ s2m_g,
    const float* __restrict__ bih, const float* __restrict__ bhh,
    const float* __restrict__ nbuf, float* __restrict__ out, int lo_, int lim){
  int t = threadIdx.x;
  int nl0 = blockIdx.x*64;
  int node0 = lo_ + nl0;
  int cnt = lim - nl0; if(cnt > 64) cnt = 64;
  int lane = t & 63, wv = t>>6;
  int lr = lane & 15, lg = lane >> 4;
  int koff = lg*8;
  int hh = wv*16 + lr;

  __shared__ u16 XH[64][264];   // cols 0..127: sve -> m2m -> hgate ; 128..255: v
  __shared__ u16 XL[64][264];
  __shared__ int gid[64];

  for(int i=t; i<64*64; i+=512){
    int n = i>>6, c4 = i&63;
    float4 val;
    if(n < cnt){
      val = (c4<32) ? ((const float4*)(nbuf + (size_t)(nl0+n)*128))[c4]
                    : ((const float4*)(v + (size_t)(node0+n)*128))[c4-32];
    } else val = make_float4(0.f,0.f,0.f,0.f);
    int c = c4<<2;
    u32 h01,l01,h23,l23;
    cvt2(val.x, val.y, h01, l01);
    cvt2(val.z, val.w, h23, l23);
    *(uint2*)&XH[n][c] = make_uint2(h01, h23);
    *(uint2*)&XL[n][c] = make_uint2(l01, l23);
  }
  if(t<64) gid[t] = (t<cnt) ? (graph_id[node0+t] & 63) : 0;
  __syncthreads();

  // ---- phase 1: m2m = leaky(E_w @ [sve; v] + E_b), K=256
  f32x4 m2m[4];
  {
    f32x4 acc[4];
#pragma unroll
    for(int ng=0;ng<4;ng++){ f32x4 z={0.f,0.f,0.f,0.f}; acc[ng]=z; }
    const u16* bh = whi + (size_t)hh*256 + koff;
    const u16* bl = wlo + (size_t)hh*256 + koff;
#pragma unroll
    for(int ks=0; ks<8; ks++){
      bf16x8 wh_ = *(const bf16x8*)(bh + ks*32);
      bf16x8 wl_ = *(const bf16x8*)(bl + ks*32);
#pragma unroll
      for(int ng=0;ng<4;ng++){
        bf16x8 ah = *(const bf16x8*)&XH[ng*16+lr][koff + ks*32];
        bf16x8 al = *(const bf16x8*)&XL[ng*16+lr][koff + ks*32];
        acc[ng] = MFMA16(ah, wh_, acc[ng], 0,0,0);
        acc[ng] = MFMA16(ah, wl_, acc[ng], 0,0,0);
        acc[ng] = MFMA16(al, wh_, acc[ng], 0,0,0);
      }
    }
    __syncthreads();
    float eb = E_b[hh];
#pragma unroll
    for(int ng=0;ng<4;ng++){
#pragma unroll
      for(int r=0;r<4;r++){
        float m = acc[ng][r] + eb;
        m = (m>0.f)? m : 0.1f*m;
        m2m[ng][r] = m;
        int n = ng*16 + lg*4 + r;
        u32 mb = __float_as_uint(m);
        u16 mh = (u16)(mb>>16);
        XH[n][hh] = mh;
        float mlr = m - __uint_as_float((u32)mh<<16);
        XL[n][hh] = (u16)(__float_as_uint(mlr)>>16);
      }
    }
    __syncthreads();
  }

  // ---- phase 2: z = sigmoid(gmA@m2m + gmA_b + gmB_lin); hgate = z*s2m + (1-z)*m2m
  {
    f32x4 acc[4];
#pragma unroll
    for(int ng=0;ng<4;ng++){ f32x4 z={0.f,0.f,0.f,0.f}; acc[ng]=z; }
    const u16* bh = whi + 32768 + (size_t)hh*128 + koff;
    const u16* bl = wlo + 32768 + (size_t)hh*128 + koff;
#pragma unroll
    for(int ks=0; ks<4; ks++){
      bf16x8 wh_ = *(const bf16x8*)(bh + ks*32);
      bf16x8 wl_ = *(const bf16x8*)(bl + ks*32);
#pragma unroll
      for(int ng=0;ng<4;ng++){
        bf16x8 ah = *(const bf16x8*)&XH[ng*16+lr][koff + ks*32];
        bf16x8 al = *(const bf16x8*)&XL[ng*16+lr][koff + ks*32];
        acc[ng] = MFMA16(ah, wh_, acc[ng], 0,0,0);
        acc[ng] = MFMA16(ah, wl_, acc[ng], 0,0,0);
        acc[ng] = MFMA16(al, wh_, acc[ng], 0,0,0);
      }
    }
    __syncthreads();
    float ab = gmA_b[hh];
#pragma unroll
    for(int ng=0;ng<4;ng++){
#pragma unroll
      for(int r=0;r<4;r++){
        int n = ng*16 + lg*4 + r;
        int g = gid[n];
        float z = sigmoidf_(acc[ng][r] + ab + gmB_lin[g*128+hh]);
        float hg = z*s2m_g[g*128+hh] + (1.f-z)*m2m[ng][r];
        u32 mb = __float_as_uint(hg);
        u16 mh = (u16)(mb>>16);
        XH[n][hh] = mh;
        float mlr = hg - __uint_as_float((u32)mh<<16);
        XL[n][hh] = (u16)(__float_as_uint(mlr)>>16);
      }
    }
    __syncthreads();
  }

  // ---- phase 3: GRU. combined rows [whh|wih] @ X=[hgate|v]; gates r, n, z --------
  {
    const u16* wGh = whi + 49152;
    const u16* wGl = wlo + 49152;
    f32x4 rr[4], nn[4];

    // gate r (j=0): fused K=256
    {
      f32x4 acc[4];
#pragma unroll
      for(int ng=0;ng<4;ng++){ f32x4 z={0.f,0.f,0.f,0.f}; acc[ng]=z; }
      const u16* ph = wGh + (size_t)hh*256 + koff;
      const u16* pl = wGl + (size_t)hh*256 + koff;
#pragma unroll
      for(int ks=0; ks<8; ks++){
        bf16x8 wh_ = *(const bf16x8*)(ph + ks*32);
        bf16x8 wl_ = *(const bf16x8*)(pl + ks*32);
#pragma unroll
        for(int ng=0;ng<4;ng++){
          bf16x8 ah = *(const bf16x8*)&XH[ng*16+lr][koff + ks*32];
          bf16x8 al = *(const bf16x8*)&XL[ng*16+lr][koff + ks*32];
          acc[ng] = MFMA16(ah, wh_, acc[ng], 0,0,0);
          acc[ng] = MFMA16(ah, wl_, acc[ng], 0,0,0);
          acc[ng] = MFMA16(al, wh_, acc[ng], 0,0,0);
        }
      }
      float bsum = bih[hh] + bhh[hh];
#pragma unroll
      for(int ng=0;ng<4;ng++)
#pragma unroll
        for(int r=0;r<4;r++) rr[ng][r] = sigmoidf_(acc[ng][r] + bsum);
    }

    // gate n (j=2): split halves (gh from hgate/whh, gi from v/wih)
    {
      f32x4 aH[4], aI[4];
#pragma unroll
      for(int ng=0;ng<4;ng++){ f32x4 z={0.f,0.f,0.f,0.f}; aH[ng]=z; aI[ng]=z; }
      const u16* ph = wGh + (size_t)(256+hh)*256 + koff;
      const u16* pl = wGl + (size_t)(256+hh)*256 + koff;
#pragma unroll
      for(int ks=0; ks<4; ks++){
        bf16x8 wh_ = *(const bf16x8*)(ph + ks*32);
        bf16x8 wl_ = *(const bf16x8*)(pl + ks*32);
#pragma unroll
        for(int ng=0;ng<4;ng++){
          bf16x8 ah = *(const bf16x8*)&XH[ng*16+lr][koff + ks*32];
          bf16x8 al = *(const bf16x8*)&XL[ng*16+lr][koff + ks*32];
          aH[ng] = MFMA16(ah, wh_, aH[ng], 0,0,0);
          aH[ng] = MFMA16(ah, wl_, aH[ng], 0,0,0);
          aH[ng] = MFMA16(al, wh_, aH[ng], 0,0,0);
        }
      }
#pragma unroll
      for(int ks=4; ks<8; ks++){
        bf16x8 wh_ = *(const bf16x8*)(ph + ks*32);
        bf16x8 wl_ = *(const bf16x8*)(pl + ks*32);
#pragma unroll
        for(int ng=0;ng<4;ng++){
          bf16x8 ah = *(const bf16x8*)&XH[ng*16+lr][koff + ks*32];
          bf16x8 al = *(const bf16x8*)&XL[ng*16+lr][koff + ks*32];
          aI[ng] = MFMA16(ah, wh_, aI[ng], 0,0,0);
          aI[ng] = MFMA16(ah, wl_, aI[ng], 0,0,0);
          aI[ng] = MFMA16(al, wh_, aI[ng], 0,0,0);
        }
      }
      float bI = bih[256+hh], bH = bhh[256+hh];
#pragma unroll
      for(int ng=0;ng<4;ng++)
#pragma unroll
        for(int r=0;r<4;r++)
          nn[ng][r] = ftanh((aI[ng][r]+bI) + rr[ng][r]*(aH[ng][r]+bH));
    }

    // gate z (j=1): fused K=256, then combine and write
    {
      f32x4 acc[4];
#pragma unroll
      for(int ng=0;ng<4;ng++){ f32x4 z={0.f,0.f,0.f,0.f}; acc[ng]=z; }
      const u16* ph = wGh + (size_t)(128+hh)*256 + koff;
      const u16* pl = wGl + (size_t)(128+hh)*256 + koff;
#pragma unroll
      for(int ks=0; ks<8; ks++){
        bf16x8 wh_ = *(const bf16x8*)(ph + ks*32);
        bf16x8 wl_ = *(const bf16x8*)(pl + ks*32);
#pragma unroll
        for(int ng=0;ng<4;ng++){
          bf16x8 ah = *(const bf16x8*)&XH[ng*16+lr][koff + ks*32];
          bf16x8 al = *(const bf16x8*)&XL[ng*16+lr][koff + ks*32];
          acc[ng] = MFMA16(ah, wh_, acc[ng], 0,0,0);
          acc[ng] = MFMA16(ah, wl_, acc[ng], 0,0,0);
          acc[ng] = MFMA16(al, wh_, acc[ng], 0,0,0);
        }
      }
      float bsum = bih[128+hh] + bhh[128+hh];
#pragma unroll
      for(int ng=0;ng<4;ng++){
#pragma unroll
        for(int r=0;r<4;r++){
          float zz = sigmoidf_(acc[ng][r] + bsum);
          int n = ng*16 + lg*4 + r;
          float hgv = bfh(XH[n][hh]) + bfh(XL[n][hh]);   // exact hi+lo reconstruct
          if(n < cnt)
            out[(size_t)(node0+n)*128 + hh] = (1.f-zz)*nn[ng][r] + zz*hgv;
        }
      }
    }
  }
}

// ---------------- supernode finish: m2s (incl. hoisted mD), gate, GRU -------------
__global__ __launch_bounds__(128,4) void k_sup2(const float* __restrict__ s,
                       const float* __restrict__ yg, const float* __restrict__ asum,
                       const float* __restrict__ s2s,
                       const float* mD_w, const float* mD_b,
                       const float* B_w, const float* B_b,
                       const float* gsA_w, const float* gsA_b,
                       const float* gsB_w, const float* gsB_b,
                       const float* wih, const float* bih, const float* whh, const float* bhh,
                       float* __restrict__ out){
  int b=blockIdx.x, h=threadIdx.x;
  __shared__ float ygl[512], m2si[512], m2sl[128], s2sl[128], sl[128], hgl[128];
  for(int j=0;j<4;j++){ int kh=h+j*128; ygl[kh]=yg[b*512+kh]; }
  s2sl[h]=s2s[b*128+h];
  sl[h]=s[b*128+h];
  __syncthreads();
  for(int j=0;j<4;j++){
    int kh=h+j*128; int k=kh>>7;
    m2si[kh] = dots(mD_w + (size_t)kh*128, &ygl[k*128]) / asum[b*4+k] + mD_b[kh];
  }
  __syncthreads();
  float acc = B_b[h];
  { const float4* q=(const float4*)(B_w + (size_t)h*512);
#pragma unroll 8
    for(int i=0;i<128;i++){
      float4 p=q[i]; int base=i*4;
      acc=fmaf(p.x,m2si[base+0],acc); acc=fmaf(p.y,m2si[base+1],acc);
      acc=fmaf(p.z,m2si[base+2],acc); acc=fmaf(p.w,m2si[base+3],acc);
    }
  }
  float m2sv = ftanh(acc);
  m2sl[h]=m2sv;
  __syncthreads();
  float zacc = dots(gsA_w+(size_t)h*128, s2sl) + gsA_b[h];
  zacc      += dots(gsB_w+(size_t)h*128, m2sl) + gsB_b[h];
  float z = sigmoidf_(zacc);
  float hg = z*m2sl[h] + (1.f-z)*s2sl[h];
  hgl[h]=hg;
  __syncthreads();
  float gi[3], gh[3];
  for(int j=0;j<3;j++){
    gi[j]=dots(wih+(size_t)(h+j*128)*128, sl)+bih[h+j*128];
    gh[j]=dots(whh+(size_t)(h+j*128)*128, hgl)+bhh[h+j*128];
  }
  float r=sigmoidf_(gi[0]+gh[0]), z2=sigmoidf_(gi[1]+gh[1]);
  float nn=ftanh(gi[2]+r*gh[2]);
  out[(size_t)N_NODES*128 + b*128 + h] = (1.f-z2)*nn + z2*hg;
}

extern "C" void kernel_launch(void* const* d_in, const int* in_sizes, int n_in,
                              void* d_out, int out_size, void* d_ws, size_t ws_size,
                              hipStream_t stream){
  const float* v   = (const float*)d_in[0];
  const float* e   = (const float*)d_in[1];
  const float* s   = (const float*)d_in[2];
  const int* src  = (const int*)d_in[3];
  const int* dst  = (const int*)d_in[4];
  const int* graph_id = (const int*)d_in[5];
  const float* A_w=(const float*)d_in[6];  const float* A_b=(const float*)d_in[7];
  const float* B_w=(const float*)d_in[8];  const float* B_b=(const float*)d_in[9];
  const float* C_w=(const float*)d_in[10]; const float* C_b=(const float*)d_in[11];
  const float* E_w=(const float*)d_in[12]; const float* E_b=(const float*)d_in[13];
  const float* K_w=(const float*)d_in[14]; const float* K_b=(const float*)d_in[15];
  const float* mA_w=(const float*)d_in[16]; const float* mA_b=(const float*)d_in[17];
  const float* mB_w=(const float*)d_in[18]; const float* mB_b=(const float*)d_in[19];
  const float* mC_w=(const float*)d_in[20]; const float* mC_b=(const float*)d_in[21];
  const float* mD_w=(const float*)d_in[22]; const float* mD_b=(const float*)d_in[23];
  const float* gmA_w=(const float*)d_in[24]; const float* gmA_b=(const float*)d_in[25];
  const float* gmB_w=(const float*)d_in[26]; const float* gmB_b=(const float*)d_in[27];
  const float* gm_wih=(const float*)d_in[28]; const float* gm_bih=(const float*)d_in[29];
  const float* gm_whh=(const float*)d_in[30]; const float* gm_bhh=(const float*)d_in[31];
  const float* gsA_w=(const float*)d_in[32]; const float* gsA_b=(const float*)d_in[33];
  const float* gsB_w=(const float*)d_in[34]; const float* gsB_b=(const float*)d_in[35];
  const float* gs_wih=(const float*)d_in[36]; const float* gs_bih=(const float*)d_in[37];
  const float* gs_whh=(const float*)d_in[38]; const float* gs_bhh=(const float*)d_in[39];

  float* ws = (float*)d_ws;
  float* asum    = ws;                  // 256
  float* yg      = asum + 256;          // 32768
  float* s2s     = yg + 32768;          // 8192
  float* s2m_g   = s2s + 8192;          // 8192
  float* gmB_lin = s2m_g + 8192;        // 8192
  float* w2      = gmB_lin + 8192;      // 32768
  u16*   whi     = (u16*)(w2 + 32768);  // 212992 u16 (hi)
  u16*   wlo     = whi + 212992;        // 212992 u16 (lo)
  const size_t small_f = 256 + 32768 + 8192*3 + 32768 + 212992;   // 303360 floats

  size_t ws_f = ws_size / 4;

  hipMemsetAsync(asum, 0, (256 + 32768) * sizeof(float), stream);

  k_prep<<<832, 256, 0, stream>>>(E_w, gmA_w, gm_wih, gm_whh, mA_w, whi, wlo);
  k_sup <<<NB, 128, 0, stream>>>(s, A_w,A_b, C_w,C_b, mB_w,mB_b,mC_w, gmB_w,gmB_b,
                                 s2s, s2m_g, w2, gmB_lin);
  k_att <<<NB*CH128, 512, 0, stream>>>(v, w2, whi + 147456, wlo + 147456,
                                       mA_b, mC_b, asum, yg);
  k_sup2<<<NB, 128, 0, stream>>>(s, yg, asum, s2s, mD_w, mD_b, B_w,B_b,
                                 gsA_w,gsA_b, gsB_w,gsB_b,
                                 gs_wih,gs_bih, gs_whh,gs_bhh, (float*)d_out);

  // CSR-gather path: offs(100002) + cursor(100002) + tsum(128) + slots(1M uint2) + nbuf
  const int SCAN_NB = (N_NODES + 1023) / 1024;         // 98
  const size_t csr_off = small_f;
  const size_t csr_f   = 100002 + 100002 + 128 + 2000000;
  const size_t need_csr = csr_off + csr_f + (size_t)N_NODES*128;

  if(ws_f >= need_csr){
    u32*   offs   = (u32*)(ws + csr_off);
    u32*   cursor = offs + 100002;
    u32*   tsum   = cursor + 100002;
    uint2* slots  = (uint2*)(tsum + 128);
    float* nbuf   = (float*)(slots + 1000000);
    hipMemsetAsync(cursor, 0, (size_t)N_NODES*sizeof(u32), stream);
    k_hist<<<1024, 256, 0, stream>>>(dst, cursor);
    k_scanA<<<SCAN_NB, 1024, 0, stream>>>(cursor, offs, tsum);
    k_scanB<<<SCAN_NB, 1024, 0, stream>>>(tsum, offs, cursor, SCAN_NB);
    k_fill<<<1024, 256, 0, stream>>>(src, dst, cursor, slots);
    k_gath<<<N_NODES, 128, 0, stream>>>(v, e, offs, slots, K_w, K_b, nbuf);
    k_node<<<(N_NODES+63)/64, 512, 0, stream>>>(v, graph_id, whi, wlo, E_b, gmA_b,
                                                gmB_lin, s2m_g, gm_bih, gm_bhh,
                                                nbuf, (float*)d_out, 0, N_NODES);
  } else {
    // fallback: chunked atomic scatter
    float* nbuf = (float*)(wlo + 212992);
    long avail = (ws_f > small_f) ? (long)(ws_f - small_f) : 0;
    long M = (avail / 128) & ~63L;
    if(M > N_NODES) M = N_NODES;
    if(M < 64) M = 64;
    for(long lo = 0; lo < N_NODES; lo += M){
      long cnt = N_NODES - lo; if(cnt > M) cnt = M;
      int ilo = (int)lo, icnt = (int)cnt;
      hipMemsetAsync(nbuf, 0, (size_t)icnt*128*sizeof(float), stream);
      k_edge<<<N_EDGES/16, 128, 0, stream>>>(v, e, src, dst, K_w, K_b, nbuf, ilo, ilo+icnt);
      k_node<<<(icnt+63)/64, 512, 0, stream>>>(v, graph_id, whi, wlo, E_b, gmA_b,
                                               gmB_lin, s2m_g, gm_bih, gm_bhh,
                                               nbuf, (float*)d_out, ilo, icnt);
    }
  }
}